// Round 3
// baseline (145.360 us; speedup 1.0000x reference)
//
#include <hip/hip_runtime.h>
#include <cstdint>
#include <math.h>

// B=128 rows, V=128000 vocab. fp32 logits/noise/temps -> int32 argmax index.
#define BB 128
#define VV 128000
#define SPLITS 25                // 128000/25 = 5120 = 256 threads * 20 elems EXACT
#define CHUNK (VV / SPLITS)      // 5120
#define TPB 256
#define STRIDE (TPB * 4)         // 1024 floats between j-steps

// Map fp32 to order-preserving uint32 (no NaNs in this problem).
__device__ __forceinline__ uint32_t sortable(float f) {
    uint32_t u = __float_as_uint(f);
    return (u & 0x80000000u) ? ~u : (u | 0x80000000u);
}

__device__ __forceinline__ uint64_t kmax(uint64_t a, uint64_t b) {
    return a > b ? a : b;
}

__global__ __launch_bounds__(TPB) void sampler_partial(
    const float* __restrict__ logits,
    const float* __restrict__ temps,
    const float* __restrict__ noise,
    uint64_t* __restrict__ pkey)
{
    const int blk = blockIdx.x;
    const int row = blk / SPLITS;
    const int seg = blk - row * SPLITS;

    const size_t rbase = (size_t)row * VV + (size_t)(seg * CHUNK) + (size_t)(threadIdx.x * 4);
    const float* lp = logits + rbase;
    const float* ep = noise  + rbase;

    // ---- 10 independent vector loads, straight-line, no branches, no deps ----
    float4 l0 = *reinterpret_cast<const float4*>(lp + 0 * STRIDE);
    float4 l1 = *reinterpret_cast<const float4*>(lp + 1 * STRIDE);
    float4 l2 = *reinterpret_cast<const float4*>(lp + 2 * STRIDE);
    float4 l3 = *reinterpret_cast<const float4*>(lp + 3 * STRIDE);
    float4 l4 = *reinterpret_cast<const float4*>(lp + 4 * STRIDE);
    float4 e0 = *reinterpret_cast<const float4*>(ep + 0 * STRIDE);
    float4 e1 = *reinterpret_cast<const float4*>(ep + 1 * STRIDE);
    float4 e2 = *reinterpret_cast<const float4*>(ep + 2 * STRIDE);
    float4 e3 = *reinterpret_cast<const float4*>(ep + 3 * STRIDE);
    float4 e4 = *reinterpret_cast<const float4*>(ep + 4 * STRIDE);

    // scalar temp load issued after the vector loads are in flight
    const float t = temps[row];
    const bool greedy = (t == 0.0f);
    const float invt = greedy ? 1.0f : (1.0f / t);

    float bv = -INFINITY;
    int   bi = 0;
    const int i0 = seg * CHUNK + (int)threadIdx.x * 4;

    // branch-free per-element: compute sampled score, predicate-select greedy
    #define PROC4(L, E, IB)                                                  \
    do {                                                                     \
        const float lv[4] = { (L).x, (L).y, (L).z, (L).w };                  \
        const float ev[4] = { (E).x, (E).y, (E).z, (E).w };                  \
        _Pragma("unroll")                                                    \
        for (int c = 0; c < 4; ++c) {                                        \
            const float samp = lv[c] * invt - logf(fmaxf(ev[c], 1e-10f));    \
            const float s = greedy ? lv[c] : samp;                           \
            if (s > bv) { bv = s; bi = (IB) + c; }                           \
        }                                                                    \
    } while (0)

    PROC4(l0, e0, i0 + 0 * STRIDE);
    PROC4(l1, e1, i0 + 1 * STRIDE);
    PROC4(l2, e2, i0 + 2 * STRIDE);
    PROC4(l3, e3, i0 + 3 * STRIDE);
    PROC4(l4, e4, i0 + 4 * STRIDE);
    #undef PROC4

    // Pack (value, ~index): u64 max == argmax with smallest-index tie-break.
    uint64_t key = ((uint64_t)sortable(bv) << 32) | (uint32_t)(~(uint32_t)bi);

    // wave64 shuffle reduction
    #pragma unroll
    for (int off = 32; off > 0; off >>= 1) {
        uint64_t ok = __shfl_down(key, off, 64);
        key = kmax(key, ok);
    }

    __shared__ uint64_t sk[TPB / 64];
    const int lane = threadIdx.x & 63;
    const int wave = threadIdx.x >> 6;
    if (lane == 0) sk[wave] = key;
    __syncthreads();
    if (threadIdx.x == 0) {
        #pragma unroll
        for (int w = 1; w < TPB / 64; ++w) key = kmax(key, sk[w]);
        pkey[blk] = key;
    }
}

__global__ __launch_bounds__(BB) void sampler_reduce(
    const uint64_t* __restrict__ pkey,
    int* __restrict__ out)
{
    const int r = threadIdx.x;                 // 128 threads, 1 block
    uint64_t key = pkey[r * SPLITS];
    #pragma unroll
    for (int s = 1; s < SPLITS; ++s)
        key = kmax(key, pkey[r * SPLITS + s]);
    out[r] = (int)(~(uint32_t)(key & 0xffffffffu));
}

extern "C" void kernel_launch(void* const* d_in, const int* in_sizes, int n_in,
                              void* d_out, int out_size, void* d_ws, size_t ws_size,
                              hipStream_t stream) {
    const float* logits = (const float*)d_in[0];   // [B, V] fp32
    const float* temps  = (const float*)d_in[1];   // [B]    fp32
    const float* noise  = (const float*)d_in[2];   // [B, V] fp32
    int* out = (int*)d_out;                        // [B]    int32

    uint64_t* pkey = (uint64_t*)d_ws;              // BB*SPLITS u64 = 25.6 KB

    sampler_partial<<<BB * SPLITS, TPB, 0, stream>>>(logits, temps, noise, pkey);
    sampler_reduce<<<1, BB, 0, stream>>>(pkey, out);
}

// Round 5
// 136.432 us; speedup vs baseline: 1.0654x; 1.0654x over previous
//
#include <hip/hip_runtime.h>
#include <cstdint>
#include <math.h>

// B=128 rows, V=128000 vocab. fp32 logits/noise/temps -> int32 argmax index.
#define BB 128
#define VV 128000
#define SPLITS 25                // 128000/25 = 5120 = 256 threads * 20 elems EXACT
#define CHUNK (VV / SPLITS)      // 5120
#define TPB 256
#define STRIDE (TPB * 4)         // 1024 floats between unroll steps
#define ITERS 5                  // 5 float4 per thread, exact

// native clang vector type — __builtin_nontemporal_load requires it
typedef float vfloat4 __attribute__((ext_vector_type(4)));

// Map fp32 to order-preserving uint32 (no NaNs in this problem).
__device__ __forceinline__ uint32_t sortable(float f) {
    uint32_t u = __float_as_uint(f);
    return (u & 0x80000000u) ? ~u : (u | 0x80000000u);
}

__device__ __forceinline__ uint64_t kmax(uint64_t a, uint64_t b) {
    return a > b ? a : b;
}

__device__ __forceinline__ vfloat4 nt_load4(const float* p) {
    // nontemporal: no L2 allocate on miss; still hits warm lines
    return __builtin_nontemporal_load(reinterpret_cast<const vfloat4*>(p));
}

__global__ __launch_bounds__(TPB) void sampler_partial(
    const float* __restrict__ logits,
    const float* __restrict__ temps,
    const float* __restrict__ noise,
    uint64_t* __restrict__ pkey)
{
    const int blk = blockIdx.x;
    const int row = blk / SPLITS;
    const int seg = blk - row * SPLITS;

    const float t = temps[row];
    const bool greedy = (t == 0.0f);          // block-uniform branch
    const float invt = greedy ? 1.0f : (1.0f / t);

    const size_t rbase = (size_t)row * VV + (size_t)(seg * CHUNK) + (size_t)(threadIdx.x * 4);
    const float* lp = logits + rbase;
    const float* ep = noise  + rbase;
    const int i0 = seg * CHUNK + (int)threadIdx.x * 4;

    float bv = -INFINITY;
    int   bi = 0;

    if (greedy) {
        // greedy rows: skip the noise stream entirely (-16.4 MB HBM)
        vfloat4 l[ITERS];
        #pragma unroll
        for (int j = 0; j < ITERS; ++j) l[j] = nt_load4(lp + j * STRIDE);
        #pragma unroll
        for (int j = 0; j < ITERS; ++j) {
            #pragma unroll
            for (int c = 0; c < 4; ++c) {
                const float v = l[j][c];
                // ascending index + strict '>' keeps FIRST occurrence
                if (v > bv) { bv = v; bi = i0 + j * STRIDE + c; }
            }
        }
    } else {
        vfloat4 l[ITERS], e[ITERS];
        #pragma unroll
        for (int j = 0; j < ITERS; ++j) l[j] = nt_load4(lp + j * STRIDE);
        #pragma unroll
        for (int j = 0; j < ITERS; ++j) e[j] = nt_load4(ep + j * STRIDE);
        #pragma unroll
        for (int j = 0; j < ITERS; ++j) {
            #pragma unroll
            for (int c = 0; c < 4; ++c) {
                const float s = l[j][c] * invt - logf(fmaxf(e[j][c], 1e-10f));
                if (s > bv) { bv = s; bi = i0 + j * STRIDE + c; }
            }
        }
    }

    // Pack (value, ~index): u64 max == argmax with smallest-index tie-break.
    uint64_t key = ((uint64_t)sortable(bv) << 32) | (uint32_t)(~(uint32_t)bi);

    // wave64 shuffle reduction
    #pragma unroll
    for (int off = 32; off > 0; off >>= 1) {
        uint64_t ok = __shfl_down(key, off, 64);
        key = kmax(key, ok);
    }

    __shared__ uint64_t sk[TPB / 64];
    const int lane = threadIdx.x & 63;
    const int wave = threadIdx.x >> 6;
    if (lane == 0) sk[wave] = key;
    __syncthreads();
    if (threadIdx.x == 0) {
        #pragma unroll
        for (int w = 1; w < TPB / 64; ++w) key = kmax(key, sk[w]);
        pkey[blk] = key;
    }
}

__global__ __launch_bounds__(BB) void sampler_reduce(
    const uint64_t* __restrict__ pkey,
    int* __restrict__ out)
{
    const int r = threadIdx.x;                 // 128 threads, 1 block
    uint64_t key = pkey[r * SPLITS];
    #pragma unroll
    for (int s = 1; s < SPLITS; ++s)
        key = kmax(key, pkey[r * SPLITS + s]);
    out[r] = (int)(~(uint32_t)(key & 0xffffffffu));
}

extern "C" void kernel_launch(void* const* d_in, const int* in_sizes, int n_in,
                              void* d_out, int out_size, void* d_ws, size_t ws_size,
                              hipStream_t stream) {
    const float* logits = (const float*)d_in[0];   // [B, V] fp32
    const float* temps  = (const float*)d_in[1];   // [B]    fp32
    const float* noise  = (const float*)d_in[2];   // [B, V] fp32
    int* out = (int*)d_out;                        // [B]    int32

    uint64_t* pkey = (uint64_t*)d_ws;              // BB*SPLITS u64 = 25.6 KB

    sampler_partial<<<BB * SPLITS, TPB, 0, stream>>>(logits, temps, noise, pkey);
    sampler_reduce<<<1, BB, 0, stream>>>(pkey, out);
}